// Round 3
// baseline (168.887 us; speedup 1.0000x reference)
//
#include <hip/hip_runtime.h>

#define DDIM 256
#define HDIM 128
#define KLEN 1024
// 2*log2(e): exp2(SCL*x) == e^{2x}
#define SCL 2.8853900817779268f

// ============ Projection -> Eq/Ek = exp2(SCL * in@W) ============
// v6: VALU-bound by construction.
// Block = 32 rows x 64 h, 256 thr (4 waves); thread = 2r x 4h (8 acc).
// A staged TRANSPOSED At[d][32r] with XOR granule swizzle g'=(r>>2)^((d>>2)&7):
//   staging writes = 2 lanes/bank (free); compute ds_read_b64 covers all 32
//   banks exactly once (16 distinct addrs, 4-lane broadcast).
// W staged row-major Wt[d][64h]; compute read = b128, 16-lane broadcast.
// Per d-step: 1 b64 + 1 b128 + 8 fma(16cy) -> LDS ~50% of pipe @4 waves.
// Grid 1088 = 1024 key (XCD-swizzled) + 64 query = 4.25 blocks/CU (24KB LDS,
// 6/CU cap -> all resident). Global prefetch in regs under compute.
// Output layouts unchanged: Eq row-major [row][128], Ek [b][h][k], exp2 applied.
__global__ __launch_bounds__(256) void proj_kernel(
    const float* __restrict__ queries, const float* __restrict__ keys,
    const float* __restrict__ W_q, const float* __restrict__ W_k,
    float* __restrict__ Eq, float* __restrict__ Ek)
{
    __shared__ union {
        struct { float At[64 * 32]; float Wt[64 * 64]; } s;  // 8 KB + 16 KB
        float t[64][36];                                     // epilogue (9 KB)
    } sm;

    const int tid = threadIdx.x;
    const int rg  = tid & 15;      // compute: rows 2rg, 2rg+1
    const int hg  = tid >> 4;      // compute: h 4hg..4hg+3
    const int ar  = tid >> 3;      // A staging: row 0..31
    const int ad4 = tid & 7;       // A staging: d-granule (covers d 0..31)
    const int wr  = tid >> 4;      // W staging: d-row 0..15 (+16i)
    const int wc  = tid & 15;      // W staging: h-granule

    int blk = blockIdx.x;
    bool iskey; int b = 0, kc0 = 0, hh, row0;
    const float* in; const float* W;
    if (blk < 1024) {
        iskey = true;
        int xcd = blk & 7, s = blk >> 3;     // s: 0..127
        b = ((s >> 6) << 3) | xcd;
        int r6 = s & 63;
        kc0 = (r6 >> 1) << 5;                // 32 k-chunks of 32
        hh  = (r6 & 1) << 6;                 // 2 h-halves of 64
        row0 = b * KLEN + kc0;
        in = keys; W = W_k;
    } else {
        iskey = false;
        int qb = blk - 1024;                 // 0..63
        row0 = (qb >> 1) << 5;
        hh   = (qb & 1) << 6;
        in = queries; W = W_q;
    }

    const float* ga = in + (size_t)(row0 + ar) * DDIM + (ad4 << 2);
    const float* gw = W + (size_t)wr * HDIM + hh + (wc << 2);

    float4 pfa0 = *(const float4*)(ga);
    float4 pfa1 = *(const float4*)(ga + 32);
    float4 pfw[4];
    #pragma unroll
    for (int i = 0; i < 4; i++)
        pfw[i] = *(const float4*)(gw + (size_t)(16 * i) * HDIM);

    float acc[2][4];
    #pragma unroll
    for (int r = 0; r < 2; r++)
        #pragma unroll
        for (int j = 0; j < 4; j++) acc[r][j] = 0.f;

    // swizzled write slot: for value (row=ar, d_l): granule (ar>>2)^((d_l>>2)&7)
    // d_l = 4*ad4+i and 32+4*ad4+i both give (d_l>>2)&7 == ad4.
    const int wg = ((((ar >> 2) ^ ad4) << 2) | (ar & 3));

    for (int dt = 0; dt < DDIM; dt += 64) {
        __syncthreads();           // prior tile's compute done
        sm.s.At[(4 * ad4 + 0) * 32 + wg] = pfa0.x;
        sm.s.At[(4 * ad4 + 1) * 32 + wg] = pfa0.y;
        sm.s.At[(4 * ad4 + 2) * 32 + wg] = pfa0.z;
        sm.s.At[(4 * ad4 + 3) * 32 + wg] = pfa0.w;
        sm.s.At[(4 * ad4 + 32) * 32 + wg] = pfa1.x;
        sm.s.At[(4 * ad4 + 33) * 32 + wg] = pfa1.y;
        sm.s.At[(4 * ad4 + 34) * 32 + wg] = pfa1.z;
        sm.s.At[(4 * ad4 + 35) * 32 + wg] = pfa1.w;
        #pragma unroll
        for (int i = 0; i < 4; i++)
            *(float4*)(&sm.s.Wt[(wr + 16 * i) * 64 + (wc << 2)]) = pfw[i];
        __syncthreads();
        if (dt < DDIM - 64) {      // prefetch next d-tile under compute
            pfa0 = *(const float4*)(ga + dt + 64);
            pfa1 = *(const float4*)(ga + dt + 96);
            #pragma unroll
            for (int i = 0; i < 4; i++)
                pfw[i] = *(const float4*)(gw + (size_t)(dt + 64 + 16 * i) * HDIM);
        }
        #pragma unroll
        for (int d4 = 0; d4 < 16; d4++) {
            const int abase = ((((rg >> 1) ^ (d4 & 7)) << 2) | ((rg & 1) << 1));
            #pragma unroll
            for (int dd = 0; dd < 4; dd++) {
                float2 a2 = *(const float2*)(&sm.s.At[(4 * d4 + dd) * 32 + abase]);
                float4 w4 = *(const float4*)(&sm.s.Wt[(4 * d4 + dd) * 64 + (hg << 2)]);
                acc[0][0] = fmaf(a2.x, w4.x, acc[0][0]);
                acc[0][1] = fmaf(a2.x, w4.y, acc[0][1]);
                acc[0][2] = fmaf(a2.x, w4.z, acc[0][2]);
                acc[0][3] = fmaf(a2.x, w4.w, acc[0][3]);
                acc[1][0] = fmaf(a2.y, w4.x, acc[1][0]);
                acc[1][1] = fmaf(a2.y, w4.y, acc[1][1]);
                acc[1][2] = fmaf(a2.y, w4.z, acc[1][2]);
                acc[1][3] = fmaf(a2.y, w4.w, acc[1][3]);
            }
        }
    }

    float e[2][4];
    #pragma unroll
    for (int r = 0; r < 2; r++)
        #pragma unroll
        for (int j = 0; j < 4; j++)
            e[r][j] = __builtin_amdgcn_exp2f(SCL * acc[r][j]);

    if (!iskey) {
        #pragma unroll
        for (int r = 0; r < 2; r++) {
            float* dst = Eq + (size_t)(row0 + 2 * rg + r) * HDIM + hh + (hg << 2);
            *(float4*)dst = make_float4(e[r][0], e[r][1], e[r][2], e[r][3]);
        }
    } else {
        // transpose 32k x 64h -> t[h][k], then 128B-chunk row stores
        __syncthreads();           // all compute reads of At/Wt done
        #pragma unroll
        for (int r = 0; r < 2; r++)
            #pragma unroll
            for (int j = 0; j < 4; j++)
                sm.t[(hg << 2) + j][(rg << 1) + r] = e[r][j];
        __syncthreads();
        float* dstb = Ek + (size_t)b * HDIM * KLEN + (size_t)hh * KLEN + kc0;
        #pragma unroll
        for (int i = 0; i < 2; i++) {
            int slot = tid + (i << 8);       // 512 float4 slots
            int h = slot >> 3, gk = slot & 7;
            float4 o = *(const float4*)(&sm.t[h][gk << 2]);
            *(float4*)(dstb + (size_t)h * KLEN + (gk << 2)) = o;
        }
    }
}

// ============ Scores + masked softmax ============
// Grid 512 (XCD-swizzled), 512 threads (8 waves). Block = (b, q-pair).
// Thread owns 2 contiguous k. tanh via r = rcp(Eq*Ek + 1): 1 trans + 2 fma
// per element. (Eq0,Eq1,w2) broadcast from LDS as one float4 per h.
__global__ __launch_bounds__(512) void score_kernel(
    const float* __restrict__ Eq, const float* __restrict__ Ek,
    const float* __restrict__ w_v, const int* __restrict__ valid_lens,
    float* __restrict__ p)
{
    __shared__ float4 eqw[HDIM];
    __shared__ float red0[8], red1[8];

    int tid = threadIdx.x, lane = tid & 63, wav = tid >> 6;
    int blk = blockIdx.x;
    int xcd = blk & 7, s = blk >> 3;
    int b = ((s >= 32) ? 8 : 0) + xcd;
    int qp = s & 31;
    int bq0 = b * 64 + qp * 2;
    int vlen = valid_lens[b];

    if (tid < HDIM) {
        float w2 = -2.0f * w_v[tid];
        eqw[tid] = make_float4(Eq[(size_t)bq0 * HDIM + tid],
                               Eq[(size_t)(bq0 + 1) * HDIM + tid], w2, 0.f);
    }
    __syncthreads();

    int k0 = tid << 1;
    float s00 = -1e30f, s01 = -1e30f, s10 = -1e30f, s11 = -1e30f;
    if (k0 < vlen) {
        const float* ekp = Ek + (size_t)b * HDIM * KLEN + k0;
        float a00 = 0.f, a01 = 0.f, a10 = 0.f, a11 = 0.f;
        #pragma unroll 4
        for (int h = 0; h < HDIM; h++) {
            float2 ek = *(const float2*)(ekp + (size_t)h * KLEN);
            float4 e  = eqw[h];
            a00 = fmaf(e.z, __builtin_amdgcn_rcpf(fmaf(e.x, ek.x, 1.f)), a00);
            a01 = fmaf(e.z, __builtin_amdgcn_rcpf(fmaf(e.x, ek.y, 1.f)), a01);
            a10 = fmaf(e.z, __builtin_amdgcn_rcpf(fmaf(e.y, ek.x, 1.f)), a10);
            a11 = fmaf(e.z, __builtin_amdgcn_rcpf(fmaf(e.y, ek.y, 1.f)), a11);
        }
        s00 = a00; s10 = a10;
        if (k0 + 1 < vlen) { s01 = a01; s11 = a11; }
    }

    float m0 = fmaxf(s00, s01), m1 = fmaxf(s10, s11);
    #pragma unroll
    for (int off = 32; off > 0; off >>= 1) {
        m0 = fmaxf(m0, __shfl_xor(m0, off, 64));
        m1 = fmaxf(m1, __shfl_xor(m1, off, 64));
    }
    if (lane == 0) { red0[wav] = m0; red1[wav] = m1; }
    __syncthreads();
    m0 = red0[0]; m1 = red1[0];
    #pragma unroll
    for (int i = 1; i < 8; i++) {
        m0 = fmaxf(m0, red0[i]);
        m1 = fmaxf(m1, red1[i]);
    }

    float e00 = __expf(s00 - m0), e01 = __expf(s01 - m0);   // masked -> exact 0
    float e10 = __expf(s10 - m1), e11 = __expf(s11 - m1);
    float t0 = e00 + e01, t1 = e10 + e11;
    #pragma unroll
    for (int off = 32; off > 0; off >>= 1) {
        t0 += __shfl_xor(t0, off, 64);
        t1 += __shfl_xor(t1, off, 64);
    }
    __syncthreads();
    if (lane == 0) { red0[wav] = t0; red1[wav] = t1; }
    __syncthreads();
    t0 = red0[0]; t1 = red1[0];
    #pragma unroll
    for (int i = 1; i < 8; i++) { t0 += red0[i]; t1 += red1[i]; }
    float inv0 = 1.0f / t0, inv1 = 1.0f / t1;

    float* p0 = p + (size_t)bq0 * KLEN + k0;
    *(float2*)(p0)        = make_float2(e00 * inv0, e01 * inv0);
    *(float2*)(p0 + KLEN) = make_float2(e10 * inv1, e11 * inv1);
}

// ============ attn @ V (fused partials + combine) ============
// v3: one kernel writes out directly. Grid 512 = (16 b x 8 qt x 4 d-quarter),
// XCD-swizzled, 256 thr. Thread = (kgroup = tid>>4 owns 16 k per 256-chunk,
// dslot = tid&15 owns 4 d). p staged ROW-MAJOR pt[8][260] (straight float4
// copies, conflict-free; read is b32 broadcast within the 16-lane kgroup).
// k clamped to vlen (p == 0 beyond -> round-to-4 safe). Cross-group reduce
// via 32KB slab union'd over pt; out stores unconditional -> poison-safe.
__global__ __launch_bounds__(256) void av_kernel(
    const float* __restrict__ p, const float* __restrict__ values,
    const int* __restrict__ valid_lens, float* __restrict__ out)
{
    __shared__ union {
        float  pt[8][260];          // 8.3 KB, pad 260 (65 granules, odd)
        float4 slab[16][8][16];     // 32 KB reduction slab
    } sm;

    int blk = blockIdx.x;
    int xcd = blk & 7, s = blk >> 3;          // s: 0..63
    int b = ((s >> 5) << 3) | xcd;
    int r = s & 31, qt = r >> 2, dh = r & 3;  // q-tile of 8, d-quarter of 64
    int tid = threadIdx.x;
    int kgroup = tid >> 4, dslot = tid & 15;
    int vlen = valid_lens[b];
    int bq0 = b * 64 + qt * 8;

    float4 acc4[8];
    #pragma unroll
    for (int q = 0; q < 8; q++) acc4[q] = make_float4(0.f, 0.f, 0.f, 0.f);

    for (int c = 0; c < 4; c++) {
        __syncthreads();           // prior chunk's pt reads done
        #pragma unroll
        for (int i = 0; i < 2; i++) {
            int slot = tid + (i << 8);        // 512 float4 slots
            int q = slot >> 6, k4 = slot & 63;
            float4 pv = *(const float4*)(p + (size_t)(bq0 + q) * KLEN + (c << 8) + (k4 << 2));
            *(float4*)(&sm.pt[q][k4 << 2]) = pv;
        }
        __syncthreads();

        int kg = (c << 8) + (kgroup << 4);    // global k base for this thread
        int cnt = vlen - kg; cnt = cnt < 0 ? 0 : (cnt > 16 ? 16 : cnt);
        int cnt4 = (cnt + 3) & ~3;            // p exactly 0 beyond vlen
        const float* vp = values + ((size_t)b * KLEN + kg) * DDIM + (dh << 6) + (dslot << 2);
        for (int j = 0; j < cnt4; j += 4) {
            #pragma unroll
            for (int jj = 0; jj < 4; jj++) {
                int kl = (kgroup << 4) + j + jj;
                float4 v = *(const float4*)(vp + (size_t)(j + jj) * DDIM);
                #pragma unroll
                for (int q = 0; q < 8; q++) {
                    float pq = sm.pt[q][kl];
                    acc4[q].x = fmaf(pq, v.x, acc4[q].x);
                    acc4[q].y = fmaf(pq, v.y, acc4[q].y);
                    acc4[q].z = fmaf(pq, v.z, acc4[q].z);
                    acc4[q].w = fmaf(pq, v.w, acc4[q].w);
                }
            }
        }
    }

    __syncthreads();               // pt dead; safe to overwrite with slab
    #pragma unroll
    for (int q = 0; q < 8; q++) sm.slab[kgroup][q][dslot] = acc4[q];
    __syncthreads();
    if (tid < 128) {
        int q = tid >> 4, ds = tid & 15;
        float4 a = sm.slab[0][q][ds];
        #pragma unroll
        for (int g = 1; g < 16; g++) {
            float4 t = sm.slab[g][q][ds];
            a.x += t.x; a.y += t.y; a.z += t.z; a.w += t.w;
        }
        *(float4*)(out + (size_t)(bq0 + q) * DDIM + (dh << 6) + (ds << 2)) = a;
    }
}

extern "C" void kernel_launch(void* const* d_in, const int* in_sizes, int n_in,
                              void* d_out, int out_size, void* d_ws, size_t ws_size,
                              hipStream_t stream) {
    const float* queries    = (const float*)d_in[0]; // [16,64,256]
    const float* keys       = (const float*)d_in[1]; // [16,1024,256]
    const float* values     = (const float*)d_in[2]; // [16,1024,256]
    const int*   valid_lens = (const int*)d_in[3];   // [16]
    const float* W_q        = (const float*)d_in[4]; // [256,128]
    const float* W_k        = (const float*)d_in[5]; // [256,128]
    const float* w_v        = (const float*)d_in[6]; // [128]

    float* Eq   = (float*)d_ws;            // 1024*128     = 512 KB
    float* Ek   = Eq + 131072;             // 16*128*1024  = 8 MB
    float* p    = Ek + 2097152;            // 1024*1024    = 4 MB

    proj_kernel<<<1088, 256, 0, stream>>>(queries, keys, W_q, W_k, Eq, Ek);
    score_kernel<<<512, 512, 0, stream>>>(Eq, Ek, w_v, valid_lens, p);
    av_kernel<<<512, 256, 0, stream>>>(p, values, valid_lens, (float*)d_out);
}

// Round 4
// 147.111 us; speedup vs baseline: 1.1480x; 1.1480x over previous
//
#include <hip/hip_runtime.h>

#define DDIM 256
#define HDIM 128
#define KLEN 1024
// 2*log2(e): exp2(SCL*x) == e^{2x}
#define SCL 2.8853900817779268f

// ============ Projection -> Eq/Ek = exp2(SCL * in@W) ============
// v2 (proven 33us): wave-uniform W (scalar s_load path) x per-lane rows.
// Block = 64 rows x 32 h = 4 waves; each wave owns 8 h, each lane owns 1 row.
// A-tile (64 rows x 64 d) in LDS, XOR-swizzled on 16B granules so each
// lane's ds_read_b128 of its own row is <=2-way (free). W operands are
// wave-uniform -> scalar loads, costing no VALU/VMEM/LDS bandwidth.
// Grid 1088 (4.25 blocks/CU): 1024 key blocks (XCD-swizzled) + 64 query.
// Output layouts: Eq row-major [row][128], Ek [b][h][k], exp2 applied.
__global__ __launch_bounds__(256) void proj_kernel(
    const float* __restrict__ queries, const float* __restrict__ keys,
    const float* __restrict__ W_q, const float* __restrict__ W_k,
    float* __restrict__ Eq, float* __restrict__ Ek)
{
    __shared__ union {
        float a[64 * 64];    // 16 KB A-tile (swizzled)
        float t[32][68];     // epilogue transpose staging (keys), pad 64->68
    } sm;

    const int tid  = threadIdx.x;
    const int lane = tid & 63;
    const int wav  = tid >> 6;

    int blk = blockIdx.x;
    bool iskey; int b = 0, kc0 = 0, hb, row0;
    const float* in; const float* W;
    if (blk < 1024) {
        iskey = true;
        int xcd = blk & 7, s = blk >> 3;
        b = ((s >> 6) << 3) | xcd;
        int r6 = s & 63;
        kc0 = (r6 >> 2) << 6;     // 16 k-chunks of 64
        hb  = (r6 & 3) << 5;      // 4 h-chunks of 32
        row0 = b * KLEN + kc0;
        in = keys; W = W_k;
    } else {
        iskey = false;
        int qrb = blk - 1024;     // 0..63
        row0 = (qrb >> 2) << 6;
        hb   = (qrb & 3) << 5;
        in = queries; W = W_q;
    }

    // wave-uniform h-base -> W accesses become scalar loads
    const int hg8 = __builtin_amdgcn_readfirstlane(wav << 3);
    const float* Wu = W + hb + hg8;

    // staging: 4 x 16B granules per thread per 64-d step, coalesced reads
    const int srow = tid >> 4;        // 0..15 (+16*i covers 64 rows)
    const int sgd  = tid & 15;        // 16B granule within 64-d row slice
    const float* gsrc = in + (size_t)(row0 + srow) * DDIM + (sgd << 2);

    float4 pf0 = *(const float4*)(gsrc);
    float4 pf1 = *(const float4*)(gsrc + 16 * DDIM);
    float4 pf2 = *(const float4*)(gsrc + 32 * DDIM);
    float4 pf3 = *(const float4*)(gsrc + 48 * DDIM);

    float acc[8];
    #pragma unroll
    for (int c = 0; c < 8; c++) acc[c] = 0.f;

    // XOR-swizzled LDS write offsets (float index): granule ^= (row & 7)
    const int w0 = (srow)      * 64 + ((sgd ^ ((srow)      & 7)) << 2);
    const int w1 = (srow + 16) * 64 + ((sgd ^ ((srow + 16) & 7)) << 2);
    const int w2 = (srow + 32) * 64 + ((sgd ^ ((srow + 32) & 7)) << 2);
    const int w3 = (srow + 48) * 64 + ((sgd ^ ((srow + 48) & 7)) << 2);

    for (int dt0 = 0; dt0 < DDIM; dt0 += 64) {
        *(float4*)(sm.a + w0) = pf0;
        *(float4*)(sm.a + w1) = pf1;
        *(float4*)(sm.a + w2) = pf2;
        *(float4*)(sm.a + w3) = pf3;
        __syncthreads();
        if (dt0 < DDIM - 64) {        // prefetch next d-tile under compute
            const float* g2 = gsrc + dt0 + 64;
            pf0 = *(const float4*)(g2);
            pf1 = *(const float4*)(g2 + 16 * DDIM);
            pf2 = *(const float4*)(g2 + 32 * DDIM);
            pf3 = *(const float4*)(g2 + 48 * DDIM);
        }
        const float* arow = sm.a + lane * 64;
        const int lx = lane & 7;
        #pragma unroll
        for (int d4 = 0; d4 < 64; d4 += 4) {
            float4 a = *(const float4*)(arow + ((((d4 >> 2)) ^ lx) << 2));
            const float* wr = Wu + (size_t)(dt0 + d4) * HDIM;
            #pragma unroll
            for (int c = 0; c < 8; c++) acc[c] = fmaf(a.x, wr[c],            acc[c]);
            #pragma unroll
            for (int c = 0; c < 8; c++) acc[c] = fmaf(a.y, wr[HDIM + c],     acc[c]);
            #pragma unroll
            for (int c = 0; c < 8; c++) acc[c] = fmaf(a.z, wr[2 * HDIM + c], acc[c]);
            #pragma unroll
            for (int c = 0; c < 8; c++) acc[c] = fmaf(a.w, wr[3 * HDIM + c], acc[c]);
        }
        __syncthreads();   // compute done before next tile overwrites LDS
    }

    float e[8];
    #pragma unroll
    for (int c = 0; c < 8; c++) e[c] = __builtin_amdgcn_exp2f(SCL * acc[c]);

    if (!iskey) {
        float* dst = Eq + (size_t)(row0 + lane) * HDIM + hb + hg8;
        *(float4*)(dst)     = make_float4(e[0], e[1], e[2], e[3]);
        *(float4*)(dst + 4) = make_float4(e[4], e[5], e[6], e[7]);
    } else {
        // transpose 64k x 32h -> t[h][k], then coalesced 256B-row stores
        #pragma unroll
        for (int c = 0; c < 8; c++) sm.t[(wav << 3) + c][lane] = e[c];
        __syncthreads();
        float* dstb = Ek + (size_t)b * HDIM * KLEN + (size_t)hb * KLEN + kc0;
        #pragma unroll
        for (int i = 0; i < 2; i++) {
            int g = tid + (i << 8);
            int h = g >> 4, k4 = (g & 15) << 2;
            float4 o = *(const float4*)(&sm.t[h][k4]);
            *(float4*)(dstb + (size_t)h * KLEN + k4) = o;
        }
    }
}

// ============ Scores + masked softmax ============
// Grid 512 (XCD-swizzled), 512 threads (8 waves). Block = (b, q-pair).
// Thread owns 2 contiguous k. tanh via r = rcp(Eq*Ek + 1): 1 trans + 2 fma
// per element. (Eq0,Eq1,w2) broadcast from LDS as one float4 per h.
__global__ __launch_bounds__(512) void score_kernel(
    const float* __restrict__ Eq, const float* __restrict__ Ek,
    const float* __restrict__ w_v, const int* __restrict__ valid_lens,
    float* __restrict__ p)
{
    __shared__ float4 eqw[HDIM];
    __shared__ float red0[8], red1[8];

    int tid = threadIdx.x, lane = tid & 63, wav = tid >> 6;
    int blk = blockIdx.x;
    int xcd = blk & 7, s = blk >> 3;
    int b = ((s >= 32) ? 8 : 0) + xcd;
    int qp = s & 31;
    int bq0 = b * 64 + qp * 2;
    int vlen = valid_lens[b];

    if (tid < HDIM) {
        float w2 = -2.0f * w_v[tid];
        eqw[tid] = make_float4(Eq[(size_t)bq0 * HDIM + tid],
                               Eq[(size_t)(bq0 + 1) * HDIM + tid], w2, 0.f);
    }
    __syncthreads();

    int k0 = tid << 1;
    float s00 = -1e30f, s01 = -1e30f, s10 = -1e30f, s11 = -1e30f;
    if (k0 < vlen) {
        const float* ekp = Ek + (size_t)b * HDIM * KLEN + k0;
        float a00 = 0.f, a01 = 0.f, a10 = 0.f, a11 = 0.f;
        #pragma unroll 4
        for (int h = 0; h < HDIM; h++) {
            float2 ek = *(const float2*)(ekp + (size_t)h * KLEN);
            float4 e  = eqw[h];
            a00 = fmaf(e.z, __builtin_amdgcn_rcpf(fmaf(e.x, ek.x, 1.f)), a00);
            a01 = fmaf(e.z, __builtin_amdgcn_rcpf(fmaf(e.x, ek.y, 1.f)), a01);
            a10 = fmaf(e.z, __builtin_amdgcn_rcpf(fmaf(e.y, ek.x, 1.f)), a10);
            a11 = fmaf(e.z, __builtin_amdgcn_rcpf(fmaf(e.y, ek.y, 1.f)), a11);
        }
        s00 = a00; s10 = a10;
        if (k0 + 1 < vlen) { s01 = a01; s11 = a11; }
    }

    float m0 = fmaxf(s00, s01), m1 = fmaxf(s10, s11);
    #pragma unroll
    for (int off = 32; off > 0; off >>= 1) {
        m0 = fmaxf(m0, __shfl_xor(m0, off, 64));
        m1 = fmaxf(m1, __shfl_xor(m1, off, 64));
    }
    if (lane == 0) { red0[wav] = m0; red1[wav] = m1; }
    __syncthreads();
    m0 = red0[0]; m1 = red1[0];
    #pragma unroll
    for (int i = 1; i < 8; i++) {
        m0 = fmaxf(m0, red0[i]);
        m1 = fmaxf(m1, red1[i]);
    }

    float e00 = __expf(s00 - m0), e01 = __expf(s01 - m0);   // masked -> exact 0
    float e10 = __expf(s10 - m1), e11 = __expf(s11 - m1);
    float t0 = e00 + e01, t1 = e10 + e11;
    #pragma unroll
    for (int off = 32; off > 0; off >>= 1) {
        t0 += __shfl_xor(t0, off, 64);
        t1 += __shfl_xor(t1, off, 64);
    }
    __syncthreads();
    if (lane == 0) { red0[wav] = t0; red1[wav] = t1; }
    __syncthreads();
    t0 = red0[0]; t1 = red1[0];
    #pragma unroll
    for (int i = 1; i < 8; i++) { t0 += red0[i]; t1 += red1[i]; }
    float inv0 = 1.0f / t0, inv1 = 1.0f / t1;

    float* p0 = p + (size_t)bq0 * KLEN + k0;
    *(float2*)(p0)        = make_float2(e00 * inv0, e01 * inv0);
    *(float2*)(p0 + KLEN) = make_float2(e10 * inv1, e11 * inv1);
}

// ============ attn @ V (k-half partials) ============
// v4: grid EXACTLY 256 = (16 b x 8 qt x 2 k-half), XCD-swizzled -> 1
// block/CU, zero tail. 4 waves; wave w owns exclusive k-slice of 128.
// Per k: one fully-coalesced global f4 (wave = entire 1KB V row), two
// broadcast ds_read_b128 for p[8q], 32 fma. vlen-clamped (p==0 beyond ->
// round-to-4 safe). LDS slab reduce; unconditional stores -> poison-safe.
__global__ __launch_bounds__(256) void av_kernel(
    const float* __restrict__ p, const float* __restrict__ values,
    const int* __restrict__ valid_lens, float* __restrict__ part)
{
    __shared__ union {
        float  pt[512][8];          // 16 KB [k-local][q]
        float4 slab[4][8][64];      // 32 KB [wave][q][d4]
    } sm;

    int blk = blockIdx.x;
    int xcd = blk & 7, s = blk >> 3;      // s: 0..31
    int b = ((s >> 4) << 3) | xcd;
    int r = s & 15, qt = r >> 1, kh = r & 1;
    int tid = threadIdx.x, lane = tid & 63, w = tid >> 6;
    int vlen = valid_lens[b];
    int bq0 = b * 64 + qt * 8;
    int kbase = kh << 9;                  // 0 or 512

    // stage p[8q][512k] -> pt[k][q] (one-time; write conflicts tolerable)
    #pragma unroll
    for (int i = 0; i < 4; i++) {
        int slot = tid + (i << 8);        // 1024 float4 slots
        int q = slot >> 7, k4 = (slot & 127) << 2;
        float4 pv = *(const float4*)(p + (size_t)(bq0 + q) * KLEN + kbase + k4);
        sm.pt[k4 + 0][q] = pv.x;
        sm.pt[k4 + 1][q] = pv.y;
        sm.pt[k4 + 2][q] = pv.z;
        sm.pt[k4 + 3][q] = pv.w;
    }
    __syncthreads();

    int kw = w << 7;                      // wave's k-local base
    int cnt = vlen - (kbase + kw); cnt = cnt < 0 ? 0 : (cnt > 128 ? 128 : cnt);
    int cnt4 = (cnt + 3) & ~3;
    const float* vb = values + ((size_t)b * KLEN + kbase + kw) * DDIM + (lane << 2);

    float4 acc[8];
    #pragma unroll
    for (int q = 0; q < 8; q++) acc[q] = make_float4(0.f, 0.f, 0.f, 0.f);

    for (int k = 0; k < cnt4; k += 4) {
        #pragma unroll
        for (int j = 0; j < 4; j++) {
            float4 v  = *(const float4*)(vb + (size_t)(k + j) * DDIM);
            float4 p0 = *(const float4*)(&sm.pt[kw + k + j][0]);
            float4 p1 = *(const float4*)(&sm.pt[kw + k + j][4]);
            float pq[8] = {p0.x, p0.y, p0.z, p0.w, p1.x, p1.y, p1.z, p1.w};
            #pragma unroll
            for (int q = 0; q < 8; q++) {
                acc[q].x = fmaf(pq[q], v.x, acc[q].x);
                acc[q].y = fmaf(pq[q], v.y, acc[q].y);
                acc[q].z = fmaf(pq[q], v.z, acc[q].z);
                acc[q].w = fmaf(pq[q], v.w, acc[q].w);
            }
        }
    }

    __syncthreads();               // pt reads done; overwrite with slab
    #pragma unroll
    for (int q = 0; q < 8; q++) sm.slab[w][q][lane] = acc[q];
    __syncthreads();
    #pragma unroll
    for (int e = 0; e < 2; e++) {
        int slot = (tid << 1) | e;         // 512 output f4 slots
        int q = slot >> 6, d4 = slot & 63;
        float4 a = sm.slab[0][q][d4];
        #pragma unroll
        for (int g = 1; g < 4; g++) {
            float4 t = sm.slab[g][q][d4];
            a.x += t.x; a.y += t.y; a.z += t.z; a.w += t.w;
        }
        *(float4*)(part + ((size_t)kh * 1024 + bq0 + q) * DDIM + (d4 << 2)) = a;
    }
}

// ============ sum 2 k-half partials ============
__global__ __launch_bounds__(256) void combine_kernel(
    const float* __restrict__ part, float* __restrict__ out)
{
    int i = blockIdx.x * 256 + threadIdx.x;        // 65536 float4 slots
    const float4* p4 = (const float4*)part;
    float4 a = p4[i];
    float4 v = p4[65536 + i];
    a.x += v.x; a.y += v.y; a.z += v.z; a.w += v.w;
    ((float4*)out)[i] = a;
}

extern "C" void kernel_launch(void* const* d_in, const int* in_sizes, int n_in,
                              void* d_out, int out_size, void* d_ws, size_t ws_size,
                              hipStream_t stream) {
    const float* queries    = (const float*)d_in[0]; // [16,64,256]
    const float* keys       = (const float*)d_in[1]; // [16,1024,256]
    const float* values     = (const float*)d_in[2]; // [16,1024,256]
    const int*   valid_lens = (const int*)d_in[3];   // [16]
    const float* W_q        = (const float*)d_in[4]; // [256,128]
    const float* W_k        = (const float*)d_in[5]; // [256,128]
    const float* w_v        = (const float*)d_in[6]; // [128]

    float* Eq   = (float*)d_ws;            // 1024*128     = 512 KB
    float* Ek   = Eq + 131072;             // 16*128*1024  = 8 MB
    float* p    = Ek + 2097152;            // 1024*1024    = 4 MB
    float* part = Ek;                      // alias: Ek dead after score; 2 MB

    proj_kernel<<<1088, 256, 0, stream>>>(queries, keys, W_q, W_k, Eq, Ek);
    score_kernel<<<512, 512, 0, stream>>>(Eq, Ek, w_v, valid_lens, p);
    av_kernel<<<256, 256, 0, stream>>>(p, values, valid_lens, part);
    combine_kernel<<<256, 256, 0, stream>>>(part, (float*)d_out);
}